// Round 3
// baseline (366.671 us; speedup 1.0000x reference)
//
#include <hip/hip_runtime.h>
#include <cstdint>
#include <cstddef>

#define IN_F 8192
#define OUT_F 8192
#define BATCH 512
#define KSPLIT 4
#define KSLICE (IN_F / KSPLIT) /* 2048 */
#define BK 32
#define NIT (KSLICE / BK) /* 64 */

typedef __bf16 bf16x8 __attribute__((ext_vector_type(8)));
typedef float floatx4 __attribute__((ext_vector_type(4)));

// fp32 -> bf16 round-to-nearest-even
__device__ __forceinline__ ushort f2bf(float f) {
  uint32_t u = __float_as_uint(f);
  u += 0x7FFFu + ((u >> 16) & 1u);
  return (ushort)(u >> 16);
}

__device__ __forceinline__ uint32_t perm(uint32_t a, uint32_t b, uint32_t s) {
  return __builtin_amdgcn_perm(a, b, s);  // D byte i selects from {a(hi):b(lo)}
}

// packed nibble dword (4 bytes, each = 2 weights: hi nibble -> even k) ->
// bf16x8 of biased weights (q+136): 0x4300|n == bf16(128+n) exactly.
__device__ __forceinline__ bf16x8 unpack8(uint32_t u) {
  uint32_t hi = (u >> 4) & 0x0F0F0F0Fu;
  uint32_t lo = u & 0x0F0F0F0Fu;
  uint32_t hl0 = perm(hi, lo, 0x01050004u);  // [hi0,lo0,hi1,lo1]
  uint32_t hl1 = perm(hi, lo, 0x03070206u);  // [hi2,lo2,hi3,lo3]
  const uint32_t c43 = 0x43434343u;
  uint4 d;
  d.x = perm(hl0, c43, 0x00050004u);  // [hi0,43,lo0,43] = bf16x2(k0,k1)
  d.y = perm(hl0, c43, 0x00070006u);
  d.z = perm(hl1, c43, 0x00050004u);
  d.w = perm(hl1, c43, 0x00070006u);
  union { uint4 u4; bf16x8 v; } cv;
  cv.u4 = d;
  return cv.v;
}

// Pass 1: x fp32 -> bf16, plus per-slice rowsums of the converted values.
__global__ __launch_bounds__(256) void cvt_rowsum(const float* __restrict__ x,
                                                  ushort* __restrict__ xb,
                                                  float* __restrict__ rowsum) {
  const int b = blockIdx.x;
  const int t = threadIdx.x;
  const float4* xr = (const float4*)(x + (size_t)b * IN_F);
  ushort4* xo = (ushort4*)(xb + (size_t)b * IN_F);
  float s[4] = {0.f, 0.f, 0.f, 0.f};
#pragma unroll
  for (int i = 0; i < 8; ++i) {
    float4 v = xr[i * 256 + t];
    ushort4 o;
    o.x = f2bf(v.x); o.y = f2bf(v.y); o.z = f2bf(v.z); o.w = f2bf(v.w);
    xo[i * 256 + t] = o;
    s[i >> 1] += __uint_as_float((uint32_t)o.x << 16) + __uint_as_float((uint32_t)o.y << 16)
               + __uint_as_float((uint32_t)o.z << 16) + __uint_as_float((uint32_t)o.w << 16);
  }
  __shared__ float red[4][4];
  const int lane = t & 63, wid = t >> 6;
#pragma unroll
  for (int j = 0; j < 4; ++j) {
    float v = s[j];
#pragma unroll
    for (int off = 32; off >= 1; off >>= 1) v += __shfl_down(v, off, 64);
    if (lane == 0) red[wid][j] = v;
  }
  __syncthreads();
  if (t < 4) rowsum[t * BATCH + b] = red[0][t] + red[1][t] + red[2][t] + red[3][t];
}

// Split-K quantized GEMM. 128x128x(KSLICE) per block, 4 waves of 64x64.
// A: global->reg double-buffer (no LDS). B: packed nibble-bytes in LDS (2KB/tile,
// double-buffered), consumer ds_read_b32 + v_perm unpack -> biased bf16.
__global__ __launch_bounds__(256, 3) void qgemm(const ushort* __restrict__ xb,
                                                const int* __restrict__ pw,
                                                const float* __restrict__ scale,
                                                const float* __restrict__ rowsum,
                                                float* __restrict__ out) {
  __shared__ uint32_t Bs[2 * 128 * 4];  // 2 bufs x 128 rows x 16B packed = 4KB

  const int tid = threadIdx.x;
  const int lane = tid & 63;
  const int w = tid >> 6;
  const int wm = w & 1, wn = w >> 1;
  const int lr = lane & 15, lq = lane >> 4;

  const int n0 = blockIdx.x * 128;
  const int m0 = blockIdx.y * 128;
  const int ks = blockIdx.z;

  // ---- A: per-lane global byte offsets for 4 fragments (16B each) ----
  const char* xbb = (const char*)xb;
  uint32_t aoff[4];
#pragma unroll
  for (int mi = 0; mi < 4; ++mi)
    aoff[mi] = (uint32_t)((m0 + wm * 64 + mi * 16 + lr) * (IN_F * 2) + ks * (KSLICE * 2) + lq * 16);

  // ---- B producer: thread t -> weight row t>>1, half h=t&1 (8 int32 = 16 k) ----
  const int r = tid >> 1, h = tid & 1;
  const char* bgp = (const char*)pw + (size_t)(n0 + r) * (IN_F * 2) + ks * (KSLICE * 2) + h * 32;
  uint32_t* bw = Bs + r * 4 + h * 2;
  const uint32_t* brd = Bs + (wn * 64 + lr) * 4 + lq;

  floatx4 acc[4][4] = {};

  // prologue: tile 0 into regs
  int4 p0 = *(const int4*)(bgp);
  int4 p1 = *(const int4*)(bgp + 16);
  bgp += 64;
  bf16x8 av[2][4];
#pragma unroll
  for (int mi = 0; mi < 4; ++mi) {
    av[0][mi] = *(const bf16x8*)(xbb + aoff[mi]);
    aoff[mi] += 64;
  }

#pragma unroll 2
  for (int it = 0; it < NIT; ++it) {
    const int cur = it & 1;
    // compact 8 int32 low-bytes -> 2 packed dwords; write 8B to LDS
    uint32_t q0 = perm((uint32_t)p0.y, (uint32_t)p0.x, 0x00000400u);
    uint32_t q1 = perm((uint32_t)p0.w, (uint32_t)p0.z, 0x00000400u);
    uint32_t q2 = perm((uint32_t)p1.y, (uint32_t)p1.x, 0x00000400u);
    uint32_t q3 = perm((uint32_t)p1.w, (uint32_t)p1.z, 0x00000400u);
    uint2 dd;
    dd.x = perm(q1, q0, 0x05040100u);  // low-bytes of int32 c0..c3
    dd.y = perm(q3, q2, 0x05040100u);  // c4..c7
    *(uint2*)(bw + cur * 512) = dd;
    __syncthreads();
    // prefetch tile it+1 (regs); a full compute phase to land
    if (it + 1 < NIT) {
      p0 = *(const int4*)(bgp);
      p1 = *(const int4*)(bgp + 16);
      bgp += 64;
#pragma unroll
      for (int mi = 0; mi < 4; ++mi) {
        av[cur ^ 1][mi] = *(const bf16x8*)(xbb + aoff[mi]);
        aoff[mi] += 64;
      }
    }
    // consume tile it
    const uint32_t* brc = brd + cur * 512;
    bf16x8 bv[4];
#pragma unroll
    for (int ni = 0; ni < 4; ++ni) bv[ni] = unpack8(brc[ni * 64]);
#pragma unroll
    for (int mi = 0; mi < 4; ++mi)
#pragma unroll
      for (int ni = 0; ni < 4; ++ni)
        acc[mi][ni] = __builtin_amdgcn_mfma_f32_16x16x32_bf16(av[cur][mi], bv[ni],
                                                              acc[mi][ni], 0, 0, 0);
  }

  // ---- epilogue: C/D layout col=lane&15, row=(lane>>4)*4+reg ----
  const int om = m0 + wm * 64 + lq * 4;
  const int on = n0 + wn * 64 + lr;
  float scv[4];
#pragma unroll
  for (int ni = 0; ni < 4; ++ni) scv[ni] = scale[on + ni * 16];
  float rsv[4][4];
#pragma unroll
  for (int mi = 0; mi < 4; ++mi)
#pragma unroll
    for (int rr = 0; rr < 4; ++rr)
      rsv[mi][rr] = rowsum[ks * BATCH + om + mi * 16 + rr];

#pragma unroll
  for (int mi = 0; mi < 4; ++mi)
#pragma unroll
    for (int ni = 0; ni < 4; ++ni) {
      const float s = scv[ni];
      float* op = out + (size_t)(om + mi * 16) * OUT_F + (on + ni * 16);
#pragma unroll
      for (int rr = 0; rr < 4; ++rr)
        atomicAdd(op + (size_t)rr * OUT_F, s * (acc[mi][ni][rr] - 136.f * rsv[mi][rr]));
    }
}

extern "C" void kernel_launch(void* const* d_in, const int* in_sizes, int n_in,
                              void* d_out, int out_size, void* d_ws, size_t ws_size,
                              hipStream_t stream) {
  const float* x = (const float*)d_in[0];
  const int* pw = (const int*)d_in[1];
  const float* scale = (const float*)d_in[2];
  float* out = (float*)d_out;

  ushort* xb = (ushort*)d_ws;  // 8 MiB bf16 copy of x
  float* rowsum = (float*)((char*)d_ws + (size_t)BATCH * IN_F * sizeof(ushort));  // KSPLIT x BATCH

  cvt_rowsum<<<BATCH, 256, 0, stream>>>(x, xb, rowsum);
  hipMemsetAsync(out, 0, (size_t)out_size * sizeof(float), stream);
  dim3 grid(OUT_F / 128, BATCH / 128, KSPLIT);
  qgemm<<<grid, 256, 0, stream>>>(xb, pw, scale, rowsum, out);
}

// Round 4
// 320.857 us; speedup vs baseline: 1.1428x; 1.1428x over previous
//
#include <hip/hip_runtime.h>
#include <cstdint>
#include <cstddef>

#define IN_F 8192
#define OUT_F 8192
#define BATCH 512
#define KSPLIT 4
#define KSLICE (IN_F / KSPLIT) /* 2048 */
#define BK 64
#define NIT (KSLICE / BK) /* 32 */

typedef __bf16 bf16x8 __attribute__((ext_vector_type(8)));
typedef float floatx4 __attribute__((ext_vector_type(4)));

// fp32 -> bf16 round-to-nearest-even
__device__ __forceinline__ ushort f2bf(float f) {
  uint32_t u = __float_as_uint(f);
  u += 0x7FFFu + ((u >> 16) & 1u);
  return (ushort)(u >> 16);
}

__device__ __forceinline__ uint32_t perm(uint32_t a, uint32_t b, uint32_t s) {
  return __builtin_amdgcn_perm(a, b, s);
}

// gather low bytes of 4 int32 -> one dword [x0,y0,z0,w0]
__device__ __forceinline__ uint32_t low4(const int4 p) {
  uint32_t qa = perm((uint32_t)p.y, (uint32_t)p.x, 0x00000400u);
  uint32_t qb = perm((uint32_t)p.w, (uint32_t)p.z, 0x00000400u);
  return perm(qb, qa, 0x05040100u);
}

// compact nibble dword (4 bytes, each: hi nibble = even k, lo = odd k) ->
// bf16x8 of biased weights (q+136): 0x4300|n == bf16(128+n) exactly.
__device__ __forceinline__ bf16x8 unpack8(uint32_t u) {
  uint32_t hi = (u >> 4) & 0x0F0F0F0Fu;
  uint32_t lo = u & 0x0F0F0F0Fu;
  uint32_t hl0 = perm(hi, lo, 0x01050004u);  // [h0,l0,h1,l1]
  uint32_t hl1 = perm(hi, lo, 0x03070206u);  // [h2,l2,h3,l3]
  const uint32_t c43 = 0x43434343u;
  uint4 d;
  d.x = perm(hl0, c43, 0x00050004u);  // [h0,43,l0,43]
  d.y = perm(hl0, c43, 0x00070006u);
  d.z = perm(hl1, c43, 0x00050004u);
  d.w = perm(hl1, c43, 0x00070006u);
  union { uint4 u4; bf16x8 v; } cv;
  cv.u4 = d;
  return cv.v;
}

__device__ __forceinline__ void async_copy16(const void* g, void* l) {
  __builtin_amdgcn_global_load_lds((__attribute__((address_space(1))) void*)(g),
                                   (__attribute__((address_space(3))) void*)(l),
                                   16, 0, 0);
}

// Pass 1: x fp32 -> bf16, plus per-slice rowsums of the converted values.
__global__ __launch_bounds__(256) void cvt_rowsum(const float* __restrict__ x,
                                                  ushort* __restrict__ xb,
                                                  float* __restrict__ rowsum) {
  const int b = blockIdx.x;
  const int t = threadIdx.x;
  const float4* xr = (const float4*)(x + (size_t)b * IN_F);
  ushort4* xo = (ushort4*)(xb + (size_t)b * IN_F);
  float s[4] = {0.f, 0.f, 0.f, 0.f};
#pragma unroll
  for (int i = 0; i < 8; ++i) {
    float4 v = xr[i * 256 + t];
    ushort4 o;
    o.x = f2bf(v.x); o.y = f2bf(v.y); o.z = f2bf(v.z); o.w = f2bf(v.w);
    xo[i * 256 + t] = o;
    s[i >> 1] += __uint_as_float((uint32_t)o.x << 16) + __uint_as_float((uint32_t)o.y << 16)
               + __uint_as_float((uint32_t)o.z << 16) + __uint_as_float((uint32_t)o.w << 16);
  }
  __shared__ float red[4][4];
  const int lane = t & 63, wid = t >> 6;
#pragma unroll
  for (int j = 0; j < 4; ++j) {
    float v = s[j];
#pragma unroll
    for (int off = 32; off >= 1; off >>= 1) v += __shfl_down(v, off, 64);
    if (lane == 0) red[wid][j] = v;
  }
  __syncthreads();
  if (t < 4) rowsum[t * BATCH + b] = red[0][t] + red[1][t] + red[2][t] + red[3][t];
}

// Split-K quantized GEMM. 128x128xKSLICE per block, 4 waves of 64x64, BK=64.
// A: async global_load_lds, XOR-swizzled chunks (conflict-free frag reads).
// B: packed int32 -> compact nibble bytes in LDS (4KB/tile), consumer v_perm
//    unpack -> biased bf16. One barrier per iter; loads issued post-barrier.
__global__ __launch_bounds__(256, 3) void qgemm(const ushort* __restrict__ xb,
                                                const int* __restrict__ pw,
                                                const float* __restrict__ scale,
                                                const float* __restrict__ rowsum,
                                                float* __restrict__ out) {
  __shared__ __align__(16) char Asm[2][16384];  // 128 rows x 128B (64 bf16), x2
  __shared__ __align__(16) char Bsm[2][4096];   // 128 rows x 32B compact, x2

  const int tid = threadIdx.x;
  const int lane = tid & 63;
  const int w = tid >> 6;
  const int wm = w & 1, wn = w >> 1;
  const int lr = lane & 15, lq = lane >> 4;

  const int n0 = blockIdx.x * 128;
  const int m0 = blockIdx.y * 128;
  const int ks = blockIdx.z;

  // ---- A staging: wave w, instr j covers rows w*32+j*8+(lane>>3) ----
  // slot s=lane&7 holds global chunk c = s ^ (row&7)  (XOR swizzle)
  const int aRow = w * 32 + (lane >> 3);
  const int ac = ((lane & 7) ^ ((lane >> 3) & 7)) * 16;
  const char* aG = (const char*)xb + (size_t)(m0 + aRow) * (IN_F * 2) + ks * (KSLICE * 2) + ac;

  // ---- B producer: thread t -> row t>>1, half h=t&1 (64B = 16 int32/iter) ----
  const int rB = tid >> 1, hB = tid & 1;
  const char* bG = (const char*)pw + (size_t)(n0 + rB) * (IN_F * 2) + ks * (KSLICE * 2) + hB * 64;

  floatx4 acc[4][4] = {};

  // prologue: issue A(0), load B(0) into regs
#pragma unroll
  for (int j = 0; j < 4; ++j)
    async_copy16(aG + (size_t)j * 8 * (IN_F * 2), Asm[0] + w * 4096 + j * 1024);
  int4 p0 = *(const int4*)(bG);
  int4 p1 = *(const int4*)(bG + 16);
  int4 p2 = *(const int4*)(bG + 32);
  int4 p3 = *(const int4*)(bG + 48);

#pragma unroll 2
  for (int it = 0; it < NIT; ++it) {
    const int c = it & 1;
    // stage compact B(it)
    int4 dd;
    dd.x = low4(p0); dd.y = low4(p1); dd.z = low4(p2); dd.w = low4(p3);
    *(int4*)(Bsm[c] + rB * 32 + hB * 16) = dd;
    __syncthreads();  // drains A(it) vmcnt + B(it) lgkm; A(it+1)/B(it+1) not yet issued
    if (it + 1 < NIT) {
      const char* ag = aG + (it + 1) * (BK * 2);
#pragma unroll
      for (int j = 0; j < 4; ++j)
        async_copy16(ag + (size_t)j * 8 * (IN_F * 2), Asm[c ^ 1] + w * 4096 + j * 1024);
      const char* bg = bG + (it + 1) * (BK * 2);
      p0 = *(const int4*)(bg);
      p1 = *(const int4*)(bg + 16);
      p2 = *(const int4*)(bg + 32);
      p3 = *(const int4*)(bg + 48);
    }
    // consume tile it
    const char* aBase = Asm[c] + (wm * 64 + lr) * 128;
    const char* bBase = Bsm[c] + (wn * 64 + lr) * 32 + lq * 4;
#pragma unroll
    for (int kk = 0; kk < 2; ++kk) {
      const int pc = ((kk * 4 + lq) ^ (lr & 7)) * 16;
      bf16x8 av[4], bv[4];
#pragma unroll
      for (int mi = 0; mi < 4; ++mi) av[mi] = *(const bf16x8*)(aBase + mi * 2048 + pc);
#pragma unroll
      for (int ni = 0; ni < 4; ++ni) bv[ni] = unpack8(*(const uint32_t*)(bBase + ni * 512 + kk * 16));
#pragma unroll
      for (int mi = 0; mi < 4; ++mi)
#pragma unroll
        for (int ni = 0; ni < 4; ++ni)
          acc[mi][ni] = __builtin_amdgcn_mfma_f32_16x16x32_bf16(av[mi], bv[ni],
                                                                acc[mi][ni], 0, 0, 0);
    }
  }

  // ---- epilogue: C/D layout col=lane&15, row=(lane>>4)*4+reg ----
  const int om = m0 + wm * 64 + lq * 4;
  const int on = n0 + wn * 64 + lr;
  float scv[4];
#pragma unroll
  for (int ni = 0; ni < 4; ++ni) scv[ni] = scale[on + ni * 16];
  float rsv[4][4];
#pragma unroll
  for (int mi = 0; mi < 4; ++mi)
#pragma unroll
    for (int rr = 0; rr < 4; ++rr)
      rsv[mi][rr] = rowsum[ks * BATCH + om + mi * 16 + rr];

#pragma unroll
  for (int mi = 0; mi < 4; ++mi)
#pragma unroll
    for (int ni = 0; ni < 4; ++ni) {
      const float s = scv[ni];
      float* op = out + (size_t)(om + mi * 16) * OUT_F + (on + ni * 16);
#pragma unroll
      for (int rr = 0; rr < 4; ++rr)
        atomicAdd(op + (size_t)rr * OUT_F, s * (acc[mi][ni][rr] - 136.f * rsv[mi][rr]));
    }
}

extern "C" void kernel_launch(void* const* d_in, const int* in_sizes, int n_in,
                              void* d_out, int out_size, void* d_ws, size_t ws_size,
                              hipStream_t stream) {
  const float* x = (const float*)d_in[0];
  const int* pw = (const int*)d_in[1];
  const float* scale = (const float*)d_in[2];
  float* out = (float*)d_out;

  ushort* xb = (ushort*)d_ws;  // 8 MiB bf16 copy of x
  float* rowsum = (float*)((char*)d_ws + (size_t)BATCH * IN_F * sizeof(ushort));  // KSPLIT x BATCH

  cvt_rowsum<<<BATCH, 256, 0, stream>>>(x, xb, rowsum);
  hipMemsetAsync(out, 0, (size_t)out_size * sizeof(float), stream);
  dim3 grid(OUT_F / 128, BATCH / 128, KSPLIT);
  qgemm<<<grid, 256, 0, stream>>>(xb, pw, scale, rowsum, out);
}

// Round 5
// 312.553 us; speedup vs baseline: 1.1731x; 1.0266x over previous
//
#include <hip/hip_runtime.h>
#include <cstdint>
#include <cstddef>

#define IN_F 8192
#define OUT_F 8192
#define BATCH 512
#define KSPLIT 4
#define KSLICE (IN_F / KSPLIT) /* 2048 */
#define BK 64
#define NIT (KSLICE / BK) /* 32 */

typedef __bf16 bf16x8 __attribute__((ext_vector_type(8)));
typedef float floatx4 __attribute__((ext_vector_type(4)));

// fp32 -> bf16 round-to-nearest-even
__device__ __forceinline__ ushort f2bf(float f) {
  uint32_t u = __float_as_uint(f);
  u += 0x7FFFu + ((u >> 16) & 1u);
  return (ushort)(u >> 16);
}

__device__ __forceinline__ uint32_t perm(uint32_t a, uint32_t b, uint32_t s) {
  return __builtin_amdgcn_perm(a, b, s);
}

// gather low bytes of 4 int32 -> one dword [x0,y0,z0,w0]
__device__ __forceinline__ uint32_t low4(const int4 p) {
  uint32_t qa = perm((uint32_t)p.y, (uint32_t)p.x, 0x00000400u);
  uint32_t qb = perm((uint32_t)p.w, (uint32_t)p.z, 0x00000400u);
  return perm(qb, qa, 0x05040100u);
}

// compact nibble dword (4 bytes, each: hi nibble = even k, lo = odd k) ->
// bf16x8 of biased weights (q+136): 0x4300|n == bf16(128+n) exactly.
__device__ __forceinline__ bf16x8 unpack8(uint32_t u) {
  uint32_t hi = (u >> 4) & 0x0F0F0F0Fu;
  uint32_t lo = u & 0x0F0F0F0Fu;
  uint32_t hl0 = perm(hi, lo, 0x01050004u);  // [h0,l0,h1,l1]
  uint32_t hl1 = perm(hi, lo, 0x03070206u);  // [h2,l2,h3,l3]
  const uint32_t c43 = 0x43434343u;
  uint4 d;
  d.x = perm(hl0, c43, 0x00050004u);
  d.y = perm(hl0, c43, 0x00070006u);
  d.z = perm(hl1, c43, 0x00050004u);
  d.w = perm(hl1, c43, 0x00070006u);
  union { uint4 u4; bf16x8 v; } cv;
  cv.u4 = d;
  return cv.v;
}

__device__ __forceinline__ void async_copy16(const void* g, void* l) {
  __builtin_amdgcn_global_load_lds((__attribute__((address_space(1))) void*)(g),
                                   (__attribute__((address_space(3))) void*)(l),
                                   16, 0, 0);
}

// Pass 1a: x fp32 -> bf16, plus per-slice rowsums of the converted values.
__global__ __launch_bounds__(256) void cvt_rowsum(const float* __restrict__ x,
                                                  ushort* __restrict__ xb,
                                                  float* __restrict__ rowsum) {
  const int b = blockIdx.x;
  const int t = threadIdx.x;
  const float4* xr = (const float4*)(x + (size_t)b * IN_F);
  ushort4* xo = (ushort4*)(xb + (size_t)b * IN_F);
  float s[4] = {0.f, 0.f, 0.f, 0.f};
#pragma unroll
  for (int i = 0; i < 8; ++i) {
    float4 v = xr[i * 256 + t];
    ushort4 o;
    o.x = f2bf(v.x); o.y = f2bf(v.y); o.z = f2bf(v.z); o.w = f2bf(v.w);
    xo[i * 256 + t] = o;
    s[i >> 1] += __uint_as_float((uint32_t)o.x << 16) + __uint_as_float((uint32_t)o.y << 16)
               + __uint_as_float((uint32_t)o.z << 16) + __uint_as_float((uint32_t)o.w << 16);
  }
  __shared__ float red[4][4];
  const int lane = t & 63, wid = t >> 6;
#pragma unroll
  for (int j = 0; j < 4; ++j) {
    float v = s[j];
#pragma unroll
    for (int off = 32; off >= 1; off >>= 1) v += __shfl_down(v, off, 64);
    if (lane == 0) red[wid][j] = v;
  }
  __syncthreads();
  if (t < 4) rowsum[t * BATCH + b] = red[0][t] + red[1][t] + red[2][t] + red[3][t];
}

// Pass 1b: compact packed_weight (one meaningful byte per int32, 134 MB)
// into dense nibble-bytes (33.5 MB). Pure streaming, BW-bound.
// 2048 blocks x 256 thr; each thread: 4 packets of 16 int32 -> 16 bytes.
#define NPKT (OUT_F * (IN_F / 2) / 16) /* 2097152 packets */
__global__ __launch_bounds__(256) void bcompact(const int* __restrict__ pw,
                                                int4* __restrict__ bc) {
  const int g = blockIdx.x * 256 + threadIdx.x;  // 524288 threads
#pragma unroll
  for (int i = 0; i < 4; ++i) {
    const size_t p = (size_t)g + (size_t)i * 524288;
    const int4* src = (const int4*)(pw + p * 16);
    int4 a = src[0], b = src[1], c = src[2], d = src[3];
    int4 o;
    o.x = (int)low4(a); o.y = (int)low4(b); o.z = (int)low4(c); o.w = (int)low4(d);
    bc[p] = o;
  }
}

// Split-K quantized GEMM on compact B. 128x128xKSLICE per block, 4 waves of
// 64x64, BK=64. ALL staging is fire-and-forget global_load_lds issued
// immediately after the barrier (a full compute phase to land before the
// next barrier's vmcnt drain). A: XOR-swizzled chunks (conflict-free frag
// reads). B: compact bytes, 1 async16/thread; consumer v_perm unpack.
__global__ __launch_bounds__(256, 4) void qgemm(const ushort* __restrict__ xb,
                                                const char* __restrict__ bc,
                                                const float* __restrict__ scale,
                                                const float* __restrict__ rowsum,
                                                float* __restrict__ out) {
  __shared__ __align__(16) char Asm[2][16384];  // 128 rows x 128B (64 bf16)
  __shared__ __align__(16) char Bsm[2][4096];   // 128 rows x 32B compact

  const int tid = threadIdx.x;
  const int lane = tid & 63;
  const int w = tid >> 6;
  const int wm = w & 1, wn = w >> 1;
  const int lr = lane & 15, lq = lane >> 4;

  const int n0 = blockIdx.x * 128;
  const int m0 = blockIdx.y * 128;
  const int ks = blockIdx.z;

  // A staging: wave w, instr j covers row w*32 + j*8 + (lane>>3);
  // slot s=lane&7 holds global chunk s ^ (row&7) (XOR swizzle).
  const int aRow = w * 32 + (lane >> 3);
  const int ac = ((lane & 7) ^ ((lane >> 3) & 7)) * 16;
  const char* aG = (const char*)xb + (size_t)(m0 + aRow) * (IN_F * 2) + ks * (KSLICE * 2) + ac;
  char* aL = Asm[0] + w * 4096;  // + j*1024 per instr; HW adds lane*16

  // B staging: thread t -> row t>>1, half t&1; LDS lands wave-contiguous.
  const char* bG = bc + (size_t)(n0 + (tid >> 1)) * (IN_F / 2) + ks * (KSLICE / 2) + (tid & 1) * 16;
  char* bL = Bsm[0] + w * 1024;

  floatx4 acc[4][4] = {};

  const char* aBase = Asm[0] + (wm * 64 + lr) * 128;
  const char* bBase = Bsm[0] + (wn * 64 + lr) * 32 + lq * 4;

  // prologue: issue tile 0
#pragma unroll
  for (int j = 0; j < 4; ++j)
    async_copy16(aG + (size_t)j * 8 * (IN_F * 2), aL + j * 1024);
  async_copy16(bG, bL);

#pragma unroll 2
  for (int it = 0; it < NIT; ++it) {
    const int c = it & 1;
    __syncthreads();  // drains tile(it) loads -- issued one full phase ago
    if (it + 1 < NIT) {
      const int nc = c ^ 1;
      const char* ag = aG + (it + 1) * (BK * 2);
#pragma unroll
      for (int j = 0; j < 4; ++j)
        async_copy16(ag + (size_t)j * 8 * (IN_F * 2), aL + nc * 16384 + j * 1024);
      async_copy16(bG + (it + 1) * (BK / 2), bL + nc * 4096);
    }
    // compute tile(it)
#pragma unroll
    for (int kk = 0; kk < 2; ++kk) {
      const int pc = ((kk * 4 + lq) ^ (lr & 7)) * 16;
      bf16x8 av[4], bv[4];
#pragma unroll
      for (int mi = 0; mi < 4; ++mi)
        av[mi] = *(const bf16x8*)(aBase + c * 16384 + mi * 2048 + pc);
#pragma unroll
      for (int ni = 0; ni < 4; ++ni)
        bv[ni] = unpack8(*(const uint32_t*)(bBase + c * 4096 + ni * 512 + kk * 16));
#pragma unroll
      for (int mi = 0; mi < 4; ++mi)
#pragma unroll
        for (int ni = 0; ni < 4; ++ni)
          acc[mi][ni] = __builtin_amdgcn_mfma_f32_16x16x32_bf16(av[mi], bv[ni],
                                                                acc[mi][ni], 0, 0, 0);
    }
  }

  // epilogue: C/D layout col=lane&15, row=(lane>>4)*4+reg
  const int om = m0 + wm * 64 + lq * 4;
  const int on = n0 + wn * 64 + lr;
  float scv[4];
#pragma unroll
  for (int ni = 0; ni < 4; ++ni) scv[ni] = scale[on + ni * 16];
  float rsv[4][4];
#pragma unroll
  for (int mi = 0; mi < 4; ++mi)
#pragma unroll
    for (int rr = 0; rr < 4; ++rr)
      rsv[mi][rr] = rowsum[ks * BATCH + om + mi * 16 + rr];

#pragma unroll
  for (int mi = 0; mi < 4; ++mi)
#pragma unroll
    for (int ni = 0; ni < 4; ++ni) {
      const float s = scv[ni];
      float* op = out + (size_t)(om + mi * 16) * OUT_F + (on + ni * 16);
#pragma unroll
      for (int rr = 0; rr < 4; ++rr)
        atomicAdd(op + (size_t)rr * OUT_F, s * (acc[mi][ni][rr] - 136.f * rsv[mi][rr]));
    }
}

extern "C" void kernel_launch(void* const* d_in, const int* in_sizes, int n_in,
                              void* d_out, int out_size, void* d_ws, size_t ws_size,
                              hipStream_t stream) {
  const float* x = (const float*)d_in[0];
  const int* pw = (const int*)d_in[1];
  const float* scale = (const float*)d_in[2];
  float* out = (float*)d_out;

  // ws layout: [0,8M) xb bf16 ; [8M,8M+8K) rowsum ; [16M,16M+33.5M) compact B
  ushort* xb = (ushort*)d_ws;
  float* rowsum = (float*)((char*)d_ws + (8u << 20));
  char* bc = (char*)d_ws + (16u << 20);

  cvt_rowsum<<<BATCH, 256, 0, stream>>>(x, xb, rowsum);
  bcompact<<<2048, 256, 0, stream>>>(pw, (int4*)bc);
  hipMemsetAsync(out, 0, (size_t)out_size * sizeof(float), stream);
  dim3 grid(OUT_F / 128, BATCH / 128, KSPLIT);
  qgemm<<<grid, 256, 0, stream>>>(xb, bc, scale, rowsum, out);
}